// Round 6
// baseline (2957.964 us; speedup 1.0000x reference)
//
#include <hip/hip_runtime.h>

// VGAE GCN encoder: radix-binned edge list + fused per-bucket LDS aggregation
// + register-pipelined fp16 MFMA GEMMs.  No CSR, no feature-wide atomics.
// n=100000, f=256, hid=128, dout=64, E=1.6M (read from in_sizes).
//
// Algebra (norm-folded): hs = (X@W1)*dis (fp16);
//   agg1: acc_i = hs_i + sum_{s in N(i)} hs_s ; h1s_i = relu(dis_i*acc_i + b1)*dis_i
//   agg2: agg2_i = dis_i*(h1s_i + sum h1s_s)  ; out = agg2 @ [Wmu|Wvar] + bias

#define HID 128
#define DOUT 64
#define NB_SHIFT 7          // 128 nodes per bucket
#define BUCKET 128
#define CHUNK 8192          // edges per binning block
#define NBMAX 1024          // max buckets (n <= 131072)

typedef _Float16 half_t;
typedef half_t f16x2 __attribute__((ext_vector_type(2)));
typedef half_t f16x4 __attribute__((ext_vector_type(4)));
typedef half_t f16x8 __attribute__((ext_vector_type(8)));
typedef float  f32x4 __attribute__((ext_vector_type(4)));

// ==================== build phase ====================

// global degree atomics + per-chunk bucket histogram (one pass over dst)
__global__ __launch_bounds__(256) void degbin_kernel(const int* __restrict__ dst,
                                                     int* __restrict__ deg,
                                                     int* __restrict__ counts,
                                                     int E, int nblocks, int NB) {
    __shared__ int hist[NBMAX];
    const int b = blockIdx.x;
    for (int t = threadIdx.x; t < NB; t += 256) hist[t] = 0;
    __syncthreads();
    const int beg = b * CHUNK;
    const int end = min(E, beg + CHUNK);
    for (int e = beg + threadIdx.x; e < end; e += 256) {
        int d = dst[e];
        atomicAdd(&deg[d], 1);
        atomicAdd(&hist[d >> NB_SHIFT], 1);
    }
    __syncthreads();
    for (int t = threadIdx.x; t < NB; t += 256)
        counts[t * nblocks + b] = hist[t];
}

__global__ void dis_kernel(const int* __restrict__ deg, float* __restrict__ dis, int n) {
    int i = blockIdx.x * blockDim.x + threadIdx.x;
    if (i < n) dis[i] = rsqrtf((float)deg[i] + 1.0f);
}

// ---- scan over flat counts: per-1024 partial (scan1) + parallel block-sum scan
//      (scan2, <=1024 blocks) + add-back (scan3) ----
__global__ __launch_bounds__(256) void scan1_kernel(const int* __restrict__ in,
                                                    int* __restrict__ out,
                                                    int* __restrict__ bsum, int n) {
    __shared__ int s[256];
    int b = blockIdx.x, t = threadIdx.x;
    int base = b * 1024 + t * 4;
    int v0 = 0, v1 = 0, v2 = 0, v3 = 0;
    if (base + 0 < n) v0 = in[base + 0];
    if (base + 1 < n) v1 = in[base + 1];
    if (base + 2 < n) v2 = in[base + 2];
    if (base + 3 < n) v3 = in[base + 3];
    int tsum = v0 + v1 + v2 + v3;
    s[t] = tsum;
    __syncthreads();
    for (int off = 1; off < 256; off <<= 1) {
        int x = (t >= off) ? s[t - off] : 0;
        __syncthreads();
        s[t] += x;
        __syncthreads();
    }
    int excl = s[t] - tsum;
    if (base + 0 < n) out[base + 0] = excl;
    if (base + 1 < n) out[base + 1] = excl + v0;
    if (base + 2 < n) out[base + 2] = excl + v0 + v1;
    if (base + 3 < n) out[base + 3] = excl + v0 + v1 + v2;
    if (t == 255) bsum[b] = s[255];
}

__global__ __launch_bounds__(1024) void scan2_kernel(int* __restrict__ bsum, int nb) {
    __shared__ int s[1024];
    int t = threadIdx.x;
    int v = (t < nb) ? bsum[t] : 0;
    s[t] = v;
    __syncthreads();
    for (int off = 1; off < 1024; off <<= 1) {
        int x = (t >= off) ? s[t - off] : 0;
        __syncthreads();
        s[t] += x;
        __syncthreads();
    }
    if (t < nb) bsum[t] = s[t] - v;   // exclusive
}

__global__ void scan3_kernel(int* __restrict__ out, const int* __restrict__ bsum, int n) {
    int i = blockIdx.x * blockDim.x + threadIdx.x;
    if (i < n) out[i] += bsum[i >> 10];
}

// LDS-staged binscatter: counting-sort the 8192-edge chunk in LDS, then write
// each (bucket,chunk) segment contiguously -> write amplification ~1.
__global__ __launch_bounds__(1024) void binscatter_kernel(const int* __restrict__ src,
                                                          const int* __restrict__ dst,
                                                          const int* __restrict__ offsets,
                                                          int2* __restrict__ binned,
                                                          int E, int nblocks, int NB) {
    __shared__ int  lhist[1024];
    __shared__ int  lbase[NBMAX];
    __shared__ int  cur[NBMAX];
    __shared__ int  goff[NBMAX];
    __shared__ int2 staged[CHUNK];
    const int b = blockIdx.x, t = threadIdx.x;
    const int beg = b * CHUNK;
    const int end = min(E, beg + CHUNK);
    const int ne  = end - beg;

    lhist[t] = 0;
    for (int k = t; k < NB; k += 1024) goff[k] = offsets[k * nblocks + b];
    __syncthreads();

    // pass 1: histogram (edges kept in registers)
    int2 regs[8];
    #pragma unroll
    for (int j = 0; j < 8; j++) {
        int e = beg + t + j * 1024;
        if (e < end) {
            regs[j] = make_int2(src[e], dst[e]);
            atomicAdd(&lhist[regs[j].y >> NB_SHIFT], 1);
        }
    }
    __syncthreads();

    // inclusive scan of lhist, then exclusive bases
    int hv = lhist[t];
    for (int off = 1; off < 1024; off <<= 1) {
        int x = (t >= off) ? lhist[t - off] : 0;
        __syncthreads();
        lhist[t] += x;
        __syncthreads();
    }
    lbase[t] = lhist[t] - hv;
    cur[t]   = lhist[t] - hv;
    __syncthreads();

    // pass 2: place into LDS staging at local rank
    #pragma unroll
    for (int j = 0; j < 8; j++) {
        int e = beg + t + j * 1024;
        if (e < end) {
            int pos = atomicAdd(&cur[regs[j].y >> NB_SHIFT], 1);
            staged[pos] = regs[j];
        }
    }
    __syncthreads();

    // pass 3: linear write-out; consecutive t -> consecutive global addrs per segment
    #pragma unroll
    for (int j = 0; j < 8; j++) {
        int tt = t + j * 1024;
        if (tt < ne) {
            int2 sd = staged[tt];
            int bkt = sd.y >> NB_SHIFT;
            binned[goff[bkt] + (tt - lbase[bkt])] = sd;
        }
    }
}

// ==================== weight prep ====================
__global__ void w1t_kernel(const float* __restrict__ W1, half_t* __restrict__ W1T) {
    int i = blockIdx.x * blockDim.x + threadIdx.x;   // 256*128
    int k = i >> 7, nn = i & 127;
    W1T[nn * 256 + k] = (half_t)W1[i];
}
__global__ void wcatt_kernel(const float* __restrict__ Wmu, const float* __restrict__ Wvar,
                             half_t* __restrict__ WcatT) {
    int i = blockIdx.x * blockDim.x + threadIdx.x;   // 128*128
    int k = i >> 7, nn = i & 127;
    float v = (nn < DOUT) ? Wmu[k * DOUT + nn] : Wvar[k * DOUT + (nn - DOUT)];
    WcatT[nn * 128 + k] = (half_t)v;
}

// ==================== MFMA GEMM1 (register-prefetch pipelined) ====================
// hs[M,128](fp16) = (A[M,256](fp32) @ W1T^T) * dis[row].  BM=64, BN=128, BK=64.
__global__ __launch_bounds__(256) void gemm1_mfma(const float* __restrict__ A,
                                                  const half_t* __restrict__ BT,
                                                  const float* __restrict__ dis,
                                                  half_t* __restrict__ C, int M) {
    __shared__ half_t As[64][72];
    __shared__ half_t Bs[128][72];
    const int tid = threadIdx.x;
    const int block_row = blockIdx.x * 64;
    const int wave = tid >> 6, lane = tid & 63;
    const int wm = (wave & 1) * 32, wn = (wave >> 1) * 64;
    const int l16 = lane & 15, quad = lane >> 4;

    f32x4 acc[2][4] = {};
    float4 pa[4];
    f16x8  pb[4];

    #pragma unroll
    for (int i = 0; i < 4; i++) {
        int idx = tid + i * 256;
        int r = idx >> 4, c = idx & 15;
        int row = block_row + r; row = row < M ? row : M - 1;
        pa[i] = ((const float4*)(A + (size_t)row * 256))[c];
    }
    #pragma unroll
    for (int i = 0; i < 4; i++) {
        int idx = tid + i * 256;
        int nr = idx >> 3, kc = idx & 7;
        pb[i] = *(const f16x8*)(BT + (size_t)nr * 256 + kc * 8);
    }

    for (int k0 = 0; k0 < 256; k0 += 64) {
        #pragma unroll
        for (int i = 0; i < 4; i++) {
            int idx = tid + i * 256;
            int r = idx >> 4, c = idx & 15;
            f16x4 hv = { (half_t)pa[i].x, (half_t)pa[i].y, (half_t)pa[i].z, (half_t)pa[i].w };
            *(f16x4*)(&As[r][c * 4]) = hv;
        }
        #pragma unroll
        for (int i = 0; i < 4; i++) {
            int idx = tid + i * 256;
            int nr = idx >> 3, kc = idx & 7;
            *(f16x8*)(&Bs[nr][kc * 8]) = pb[i];
        }
        __syncthreads();

        if (k0 < 192) {
            #pragma unroll
            for (int i = 0; i < 4; i++) {
                int idx = tid + i * 256;
                int r = idx >> 4, c = idx & 15;
                int row = block_row + r; row = row < M ? row : M - 1;
                pa[i] = ((const float4*)(A + (size_t)row * 256 + k0 + 64))[c];
            }
            #pragma unroll
            for (int i = 0; i < 4; i++) {
                int idx = tid + i * 256;
                int nr = idx >> 3, kc = idx & 7;
                pb[i] = *(const f16x8*)(BT + (size_t)nr * 256 + k0 + 64 + kc * 8);
            }
        }

        #pragma unroll
        for (int ks = 0; ks < 2; ks++) {
            f16x8 af[2], bf[4];
            #pragma unroll
            for (int mt = 0; mt < 2; mt++)
                af[mt] = *(const f16x8*)(&As[wm + mt * 16 + l16][ks * 32 + quad * 8]);
            #pragma unroll
            for (int nt = 0; nt < 4; nt++)
                bf[nt] = *(const f16x8*)(&Bs[wn + nt * 16 + l16][ks * 32 + quad * 8]);
            #pragma unroll
            for (int mt = 0; mt < 2; mt++)
                #pragma unroll
                for (int nt = 0; nt < 4; nt++)
                    acc[mt][nt] = __builtin_amdgcn_mfma_f32_16x16x32_f16(af[mt], bf[nt], acc[mt][nt], 0, 0, 0);
        }
        __syncthreads();
    }

    #pragma unroll
    for (int mt = 0; mt < 2; mt++) {
        #pragma unroll
        for (int r = 0; r < 4; r++) {
            int row = block_row + wm + mt * 16 + quad * 4 + r;
            if (row < M) {
                float d = dis[row];
                #pragma unroll
                for (int nt = 0; nt < 4; nt++) {
                    int col = wn + nt * 16 + l16;
                    C[(size_t)row * 128 + col] = (half_t)(acc[mt][nt][r] * d);
                }
            }
        }
    }
}

// ==================== MFMA GEMM2 (pipelined) ====================
__global__ __launch_bounds__(256) void gemm2_mfma(const half_t* __restrict__ A,
                                                  const half_t* __restrict__ BT,
                                                  const float* __restrict__ bmu,
                                                  const float* __restrict__ bvar,
                                                  float* __restrict__ out_mu,
                                                  float* __restrict__ out_sig, int M) {
    __shared__ half_t As[64][72];
    __shared__ half_t Bs[128][72];
    const int tid = threadIdx.x;
    const int block_row = blockIdx.x * 64;
    const int wave = tid >> 6, lane = tid & 63;
    const int wm = (wave & 1) * 32, wn = (wave >> 1) * 64;
    const int l16 = lane & 15, quad = lane >> 4;

    f32x4 acc[2][4] = {};
    f16x8 pa[2], pb[4];

    #pragma unroll
    for (int i = 0; i < 2; i++) {
        int idx = tid + i * 256;
        int r = idx >> 3, kc = idx & 7;
        int row = block_row + r; row = row < M ? row : M - 1;
        pa[i] = *(const f16x8*)(A + (size_t)row * 128 + kc * 8);
    }
    #pragma unroll
    for (int i = 0; i < 4; i++) {
        int idx = tid + i * 256;
        int nr = idx >> 3, kc = idx & 7;
        pb[i] = *(const f16x8*)(BT + (size_t)nr * 128 + kc * 8);
    }

    for (int k0 = 0; k0 < 128; k0 += 64) {
        #pragma unroll
        for (int i = 0; i < 2; i++) {
            int idx = tid + i * 256;
            int r = idx >> 3, kc = idx & 7;
            *(f16x8*)(&As[r][kc * 8]) = pa[i];
        }
        #pragma unroll
        for (int i = 0; i < 4; i++) {
            int idx = tid + i * 256;
            int nr = idx >> 3, kc = idx & 7;
            *(f16x8*)(&Bs[nr][kc * 8]) = pb[i];
        }
        __syncthreads();

        if (k0 < 64) {
            #pragma unroll
            for (int i = 0; i < 2; i++) {
                int idx = tid + i * 256;
                int r = idx >> 3, kc = idx & 7;
                int row = block_row + r; row = row < M ? row : M - 1;
                pa[i] = *(const f16x8*)(A + (size_t)row * 128 + 64 + kc * 8);
            }
            #pragma unroll
            for (int i = 0; i < 4; i++) {
                int idx = tid + i * 256;
                int nr = idx >> 3, kc = idx & 7;
                pb[i] = *(const f16x8*)(BT + (size_t)nr * 128 + 64 + kc * 8);
            }
        }

        #pragma unroll
        for (int ks = 0; ks < 2; ks++) {
            f16x8 af[2], bf[4];
            #pragma unroll
            for (int mt = 0; mt < 2; mt++)
                af[mt] = *(const f16x8*)(&As[wm + mt * 16 + l16][ks * 32 + quad * 8]);
            #pragma unroll
            for (int nt = 0; nt < 4; nt++)
                bf[nt] = *(const f16x8*)(&Bs[wn + nt * 16 + l16][ks * 32 + quad * 8]);
            #pragma unroll
            for (int mt = 0; mt < 2; mt++)
                #pragma unroll
                for (int nt = 0; nt < 4; nt++)
                    acc[mt][nt] = __builtin_amdgcn_mfma_f32_16x16x32_f16(af[mt], bf[nt], acc[mt][nt], 0, 0, 0);
        }
        __syncthreads();
    }

    float bias[4];
    int cols[4];
    #pragma unroll
    for (int nt = 0; nt < 4; nt++) {
        int col = wn + nt * 16 + l16;
        cols[nt] = col;
        bias[nt] = (col < DOUT) ? bmu[col] : bvar[col - DOUT];
    }

    #pragma unroll
    for (int mt = 0; mt < 2; mt++) {
        #pragma unroll
        for (int r = 0; r < 4; r++) {
            int row = block_row + wm + mt * 16 + quad * 4 + r;
            if (row < M) {
                #pragma unroll
                for (int nt = 0; nt < 4; nt++) {
                    int col = cols[nt];
                    float v = acc[mt][nt][r] + bias[nt];
                    if (col < DOUT) out_mu[(size_t)row * DOUT + col] = v;
                    else            out_sig[(size_t)row * DOUT + (col - DOUT)] = v;
                }
            }
        }
    }
}

// ==================== fused per-bucket LDS aggregation ====================
// One block per 128-node bucket; 64 KB fp32 accumulator in LDS; one wave per
// edge: 256B gather of hin[src], lane adds its f16x2 via 2x ds_add_f32
// (stride-2 -> 2-way bank alias, free).  Epilogue fuses dis/bias/relu + fp16 store.
template <bool LAYER1>
__global__ __launch_bounds__(1024) void agg_fused(const int2* __restrict__ binned,
                                                  const int* __restrict__ offsets,
                                                  const float* __restrict__ dis,
                                                  const half_t* __restrict__ hin,
                                                  half_t* __restrict__ hout,
                                                  const float* __restrict__ bias,
                                                  int E, int nblocks, int NB, int n) {
    __shared__ float acc[BUCKET][HID];
    const int b = blockIdx.x, t = threadIdx.x;
    const int base = offsets[b * nblocks];
    const int bend = (b + 1 < NB) ? offsets[(b + 1) * nblocks] : E;
    const int node0 = b << NB_SHIFT;
    const f16x2* hv = (const f16x2*)hin;

    // init with self-loop term (hin already carries the dis factor)
    #pragma unroll
    for (int j = 0; j < 8; j++) {
        int idx = t + j * 1024;          // 0..8191 = 128 nodes x 64 f16x2
        int nl = idx >> 6, fp = idx & 63;
        int gn = node0 + nl;
        float vx = 0.f, vy = 0.f;
        if (gn < n) { f16x2 h2 = hv[(size_t)gn * 64 + fp]; vx = (float)h2[0]; vy = (float)h2[1]; }
        acc[nl][fp * 2]     = vx;
        acc[nl][fp * 2 + 1] = vy;
    }
    __syncthreads();

    const int wid = t >> 6, lane = t & 63;
    int e = base + wid * 4;

    if (e + 4 <= bend) {
        int2 s0 = binned[e], s1 = binned[e + 1], s2 = binned[e + 2], s3 = binned[e + 3];
        for (;;) {
            int enext = e + 64;
            bool more = (enext + 4 <= bend);
            int2 n0, n1, n2, n3;
            if (more) { n0 = binned[enext]; n1 = binned[enext + 1];
                        n2 = binned[enext + 2]; n3 = binned[enext + 3]; }
            f16x2 a0 = hv[(size_t)s0.x * 64 + lane];
            f16x2 a1 = hv[(size_t)s1.x * 64 + lane];
            f16x2 a2 = hv[(size_t)s2.x * 64 + lane];
            f16x2 a3 = hv[(size_t)s3.x * 64 + lane];
            atomicAdd(&acc[s0.y & (BUCKET - 1)][lane * 2],     (float)a0[0]);
            atomicAdd(&acc[s0.y & (BUCKET - 1)][lane * 2 + 1], (float)a0[1]);
            atomicAdd(&acc[s1.y & (BUCKET - 1)][lane * 2],     (float)a1[0]);
            atomicAdd(&acc[s1.y & (BUCKET - 1)][lane * 2 + 1], (float)a1[1]);
            atomicAdd(&acc[s2.y & (BUCKET - 1)][lane * 2],     (float)a2[0]);
            atomicAdd(&acc[s2.y & (BUCKET - 1)][lane * 2 + 1], (float)a2[1]);
            atomicAdd(&acc[s3.y & (BUCKET - 1)][lane * 2],     (float)a3[0]);
            atomicAdd(&acc[s3.y & (BUCKET - 1)][lane * 2 + 1], (float)a3[1]);
            e = enext;
            if (!more) break;
            s0 = n0; s1 = n1; s2 = n2; s3 = n3;
        }
    }
    // tail: this wave's final partial 4-block (if any)
    for (int q = e; q < min(e + 4, bend); q++) {
        if (q < base) continue;
        int2 sd = binned[q];
        f16x2 a0 = hv[(size_t)sd.x * 64 + lane];
        atomicAdd(&acc[sd.y & (BUCKET - 1)][lane * 2],     (float)a0[0]);
        atomicAdd(&acc[sd.y & (BUCKET - 1)][lane * 2 + 1], (float)a0[1]);
    }
    __syncthreads();

    // epilogue
    #pragma unroll
    for (int j = 0; j < 8; j++) {
        int idx = t + j * 1024;
        int nl = idx >> 6, fp = idx & 63;
        int gn = node0 + nl;
        if (gn < n) {
            float di = dis[gn];
            float vx = acc[nl][fp * 2], vy = acc[nl][fp * 2 + 1];
            if (LAYER1) {
                float2 bb = ((const float2*)bias)[fp];
                vx = vx * di + bb.x; vy = vy * di + bb.y;
                vx = (vx > 0.f ? vx : 0.f) * di;
                vy = (vy > 0.f ? vy : 0.f) * di;
            } else {
                vx *= di; vy *= di;
            }
            f16x2 o = { (half_t)vx, (half_t)vy };
            ((f16x2*)hout)[(size_t)gn * 64 + fp] = o;
        }
    }
}

extern "C" void kernel_launch(void* const* d_in, const int* in_sizes, int n_in,
                              void* d_out, int out_size, void* d_ws, size_t ws_size,
                              hipStream_t stream) {
    const float* x    = (const float*)d_in[0];
    const int*   ei   = (const int*)d_in[1];
    const float* W1   = (const float*)d_in[2];
    const float* b1   = (const float*)d_in[3];
    const float* Wmu  = (const float*)d_in[4];
    const float* bmu  = (const float*)d_in[5];
    const float* Wvar = (const float*)d_in[6];
    const float* bvar = (const float*)d_in[7];

    const int n = in_sizes[0] / 256;     // 100000
    const int E = in_sizes[1] / 2;       // 1600000
    const int* src = ei;
    const int* dst = ei + E;

    const int NB      = (n + BUCKET - 1) >> NB_SHIFT;   // 782
    const int nblocks = (E + CHUNK - 1) / CHUNK;        // 196
    const int flat    = NB * nblocks;
    const int nb_scan = (flat + 1023) / 1024;           // <= 1024

    char* ws = (char*)d_ws;
    size_t off = 0;
    auto alloc = [&](size_t bytes) { void* p = ws + off; off = (off + bytes + 255) & ~(size_t)255; return p; };
    int*    deg     = (int*)   alloc((size_t)n * 4);
    float*  dis     = (float*) alloc((size_t)n * 4);
    int*    counts  = (int*)   alloc((size_t)flat * 4);
    int*    offsets = (int*)   alloc((size_t)flat * 4);
    int*    bsum    = (int*)   alloc((size_t)nb_scan * 4 + 256);
    int2*   binned  = (int2*)  alloc((size_t)E * 8);
    half_t* W1T     = (half_t*)alloc((size_t)256 * HID * 2);
    half_t* WcatT   = (half_t*)alloc((size_t)HID * HID * 2);
    half_t* hs      = (half_t*)alloc((size_t)n * HID * 2);  // gemm1 out (pre-scaled); reused as agg2
    half_t* h1s     = (half_t*)alloc((size_t)n * HID * 2);  // relu out (pre-scaled)
    half_t* agg2    = hs;                                   // alias: hs dead after agg1

    float* out_mu  = (float*)d_out;
    float* out_sig = (float*)d_out + (size_t)n * DOUT;

    // build
    hipMemsetAsync(deg, 0, (size_t)n * 4, stream);
    degbin_kernel<<<nblocks, 256, 0, stream>>>(dst, deg, counts, E, nblocks, NB);
    dis_kernel<<<(n + 255) / 256, 256, 0, stream>>>(deg, dis, n);
    scan1_kernel<<<nb_scan, 256, 0, stream>>>(counts, offsets, bsum, flat);
    scan2_kernel<<<1, 1024, 0, stream>>>(bsum, nb_scan);
    scan3_kernel<<<(flat + 255) / 256, 256, 0, stream>>>(offsets, bsum, flat);
    binscatter_kernel<<<nblocks, 1024, 0, stream>>>(src, dst, offsets, binned, E, nblocks, NB);

    // weights
    w1t_kernel<<<(256 * HID) / 256, 256, 0, stream>>>(W1, W1T);
    wcatt_kernel<<<(HID * HID) / 256, 256, 0, stream>>>(Wmu, Wvar, WcatT);

    // dense + sparse pipeline
    gemm1_mfma<<<(n + 63) / 64, 256, 0, stream>>>(x, W1T, dis, hs, n);
    agg_fused<true><<<NB, 1024, 0, stream>>>(binned, offsets, dis, hs, h1s, b1, E, nblocks, NB, n);
    agg_fused<false><<<NB, 1024, 0, stream>>>(binned, offsets, dis, h1s, agg2, nullptr, E, nblocks, NB, n);
    gemm2_mfma<<<(n + 63) / 64, 256, 0, stream>>>(agg2, WcatT, bmu, bvar, out_mu, out_sig, n);
}

// Round 7
// 383.529 us; speedup vs baseline: 7.7125x; 7.7125x over previous
//
#include <hip/hip_runtime.h>

// VGAE GCN encoder: radix-binned CSR build (staged, coalesced) + pre-scaled
// CSR gather aggregation + register-pipelined fp16 MFMA GEMMs.
// n=100000, f=256, hid=128, dout=64, E=1.6M (read from in_sizes).
//
// Algebra (norm-folded): hs = (X@W1)*dis (fp16);
//   agg1: acc_i = hs_i + sum_{s in N(i)} hs_s ; h1s_i = relu(dis_i*acc_i + b1)*dis_i
//   agg2: agg2_i = dis_i*(h1s_i + sum h1s_s)  ; out = agg2 @ [Wmu|Wvar] + bias
//
// NOTE (round-6 post-mortem): fused per-bucket LDS-atomic aggregation regressed
// 20x (VALUBusy 2.2%) — lane-scattered ds_add_f32 serializes. Register
// accumulation per node is the right structure on CDNA4.

#define HID 128
#define DOUT 64
#define NB_SHIFT 8          // 256 nodes per bucket
#define CHUNK 8192          // edges per binning block
#define MAXNB 400           // max buckets (n <= 102400)

typedef _Float16 half_t;
typedef half_t f16x4 __attribute__((ext_vector_type(4)));
typedef half_t f16x8 __attribute__((ext_vector_type(8)));
typedef float  f32x4 __attribute__((ext_vector_type(4)));

// ==================== CSR build ====================

__global__ __launch_bounds__(256) void bincount_kernel(const int* __restrict__ dst,
                                                       int* __restrict__ counts,
                                                       int E, int nblocks, int NB) {
    __shared__ int hist[MAXNB];
    const int b = blockIdx.x;
    for (int t = threadIdx.x; t < NB; t += 256) hist[t] = 0;
    __syncthreads();
    const int beg = b * CHUNK;
    const int end = min(E, beg + CHUNK);
    for (int e = beg + threadIdx.x; e < end; e += 256)
        atomicAdd(&hist[dst[e] >> NB_SHIFT], 1);
    __syncthreads();
    for (int t = threadIdx.x; t < NB; t += 256)
        counts[t * nblocks + b] = hist[t];
}

__global__ __launch_bounds__(256) void scan1_kernel(const int* __restrict__ in,
                                                    int* __restrict__ out,
                                                    int* __restrict__ bsum, int n) {
    __shared__ int s[256];
    int b = blockIdx.x, t = threadIdx.x;
    int base = b * 1024 + t * 4;
    int v0 = 0, v1 = 0, v2 = 0, v3 = 0;
    if (base + 0 < n) v0 = in[base + 0];
    if (base + 1 < n) v1 = in[base + 1];
    if (base + 2 < n) v2 = in[base + 2];
    if (base + 3 < n) v3 = in[base + 3];
    int tsum = v0 + v1 + v2 + v3;
    s[t] = tsum;
    __syncthreads();
    for (int off = 1; off < 256; off <<= 1) {
        int x = (t >= off) ? s[t - off] : 0;
        __syncthreads();
        s[t] += x;
        __syncthreads();
    }
    int excl = s[t] - tsum;
    if (base + 0 < n) out[base + 0] = excl;
    if (base + 1 < n) out[base + 1] = excl + v0;
    if (base + 2 < n) out[base + 2] = excl + v0 + v1;
    if (base + 3 < n) out[base + 3] = excl + v0 + v1 + v2;
    if (t == 255) bsum[b] = s[255];
}

// parallel single-block scan of block sums (nb <= 1024)
__global__ __launch_bounds__(1024) void scan2_kernel(int* __restrict__ bsum, int nb) {
    __shared__ int s[1024];
    int t = threadIdx.x;
    int v = (t < nb) ? bsum[t] : 0;
    s[t] = v;
    __syncthreads();
    for (int off = 1; off < 1024; off <<= 1) {
        int x = (t >= off) ? s[t - off] : 0;
        __syncthreads();
        s[t] += x;
        __syncthreads();
    }
    if (t < nb) bsum[t] = s[t] - v;   // exclusive
}

__global__ void scan3_kernel(int* __restrict__ out, const int* __restrict__ bsum, int n) {
    int i = blockIdx.x * blockDim.x + threadIdx.x;
    if (i < n) out[i] += bsum[i >> 10];
}

// LDS-staged binscatter: counting-sort the 8192-edge chunk in LDS, then write
// each (bucket,chunk) segment contiguously -> write amplification ~1.
__global__ __launch_bounds__(1024) void binscatter_kernel(const int* __restrict__ src,
                                                          const int* __restrict__ dst,
                                                          const int* __restrict__ offsets,
                                                          int2* __restrict__ binned,
                                                          int E, int nblocks, int NB) {
    __shared__ int  lhist[1024];
    __shared__ int  lbase[1024];
    __shared__ int  cur[1024];
    __shared__ int  goff[MAXNB];
    __shared__ int2 staged[CHUNK];
    const int b = blockIdx.x, t = threadIdx.x;
    const int beg = b * CHUNK;
    const int end = min(E, beg + CHUNK);
    const int ne  = end - beg;

    lhist[t] = 0;
    for (int k = t; k < NB; k += 1024) goff[k] = offsets[k * nblocks + b];
    __syncthreads();

    // pass 1: histogram (edges kept in registers)
    int2 regs[8];
    #pragma unroll
    for (int j = 0; j < 8; j++) {
        int e = beg + t + j * 1024;
        if (e < end) {
            regs[j] = make_int2(src[e], dst[e]);
            atomicAdd(&lhist[regs[j].y >> NB_SHIFT], 1);
        }
    }
    __syncthreads();

    // inclusive scan of lhist -> exclusive bases
    int hv = lhist[t];
    for (int off = 1; off < 1024; off <<= 1) {
        int x = (t >= off) ? lhist[t - off] : 0;
        __syncthreads();
        lhist[t] += x;
        __syncthreads();
    }
    lbase[t] = lhist[t] - hv;
    cur[t]   = lhist[t] - hv;
    __syncthreads();

    // pass 2: place into LDS staging at local rank
    #pragma unroll
    for (int j = 0; j < 8; j++) {
        int e = beg + t + j * 1024;
        if (e < end) {
            int pos = atomicAdd(&cur[regs[j].y >> NB_SHIFT], 1);
            staged[pos] = regs[j];
        }
    }
    __syncthreads();

    // pass 3: linear write-out; consecutive t -> consecutive global addrs per segment
    #pragma unroll
    for (int j = 0; j < 8; j++) {
        int tt = t + j * 1024;
        if (tt < ne) {
            int2 sd = staged[tt];
            int bkt = sd.y >> NB_SHIFT;
            binned[goff[bkt] + (tt - lbase[bkt])] = sd;
        }
    }
}

// one WG per 256-node bucket: local degree hist -> local scan -> dis/rowptr_end
// (coalesced) -> place col within the bucket's 16KB window.
__global__ __launch_bounds__(256) void csrbuild_kernel(const int2* __restrict__ binned,
                                                       const int* __restrict__ offsets,
                                                       int* __restrict__ rowptr_end,
                                                       int* __restrict__ colA,
                                                       float* __restrict__ dis,
                                                       int E, int nblocks, int NB, int n) {
    __shared__ int deg[256];
    __shared__ int sc[256];
    __shared__ int cur[256];
    const int b = blockIdx.x;
    const int t = threadIdx.x;
    const int base = offsets[b * nblocks];
    const int bend = (b + 1 < NB) ? offsets[(b + 1) * nblocks] : E;

    deg[t] = 0;
    __syncthreads();
    for (int e = base + t; e < bend; e += 256)
        atomicAdd(&deg[binned[e].y & 255], 1);
    __syncthreads();

    int v = deg[t];
    sc[t] = v;
    __syncthreads();
    for (int off = 1; off < 256; off <<= 1) {
        int x = (t >= off) ? sc[t - off] : 0;
        __syncthreads();
        sc[t] += x;
        __syncthreads();
    }
    int incl = sc[t];
    int node = (b << NB_SHIFT) + t;
    if (node < n) {
        rowptr_end[node] = base + incl;
        dis[node] = rsqrtf((float)v + 1.0f);
    }
    cur[t] = base + incl - v;
    __syncthreads();

    for (int e = base + t; e < bend; e += 256) {
        int2 sd = binned[e];
        int pos = atomicAdd(&cur[sd.y & 255], 1);
        colA[pos] = sd.x;
    }
}

// ==================== weight prep ====================
__global__ void w1t_kernel(const float* __restrict__ W1, half_t* __restrict__ W1T) {
    int i = blockIdx.x * blockDim.x + threadIdx.x;   // 256*128
    int k = i >> 7, nn = i & 127;
    W1T[nn * 256 + k] = (half_t)W1[i];
}
__global__ void wcatt_kernel(const float* __restrict__ Wmu, const float* __restrict__ Wvar,
                             half_t* __restrict__ WcatT) {
    int i = blockIdx.x * blockDim.x + threadIdx.x;   // 128*128
    int k = i >> 7, nn = i & 127;
    float v = (nn < DOUT) ? Wmu[k * DOUT + nn] : Wvar[k * DOUT + (nn - DOUT)];
    WcatT[nn * 128 + k] = (half_t)v;
}

// ==================== MFMA GEMM1 (register-prefetch pipelined) ====================
// hs[M,128](fp16) = (A[M,256](fp32) @ W1T^T) * dis[row].  BM=64, BN=128, BK=64.
__global__ __launch_bounds__(256) void gemm1_mfma(const float* __restrict__ A,
                                                  const half_t* __restrict__ BT,
                                                  const float* __restrict__ dis,
                                                  half_t* __restrict__ C, int M) {
    __shared__ half_t As[64][72];
    __shared__ half_t Bs[128][72];
    const int tid = threadIdx.x;
    const int block_row = blockIdx.x * 64;
    const int wave = tid >> 6, lane = tid & 63;
    const int wm = (wave & 1) * 32, wn = (wave >> 1) * 64;
    const int l16 = lane & 15, quad = lane >> 4;

    f32x4 acc[2][4] = {};
    float4 pa[4];
    f16x8  pb[4];

    #pragma unroll
    for (int i = 0; i < 4; i++) {
        int idx = tid + i * 256;
        int r = idx >> 4, c = idx & 15;
        int row = block_row + r; row = row < M ? row : M - 1;
        pa[i] = ((const float4*)(A + (size_t)row * 256))[c];
    }
    #pragma unroll
    for (int i = 0; i < 4; i++) {
        int idx = tid + i * 256;
        int nr = idx >> 3, kc = idx & 7;
        pb[i] = *(const f16x8*)(BT + (size_t)nr * 256 + kc * 8);
    }

    for (int k0 = 0; k0 < 256; k0 += 64) {
        #pragma unroll
        for (int i = 0; i < 4; i++) {
            int idx = tid + i * 256;
            int r = idx >> 4, c = idx & 15;
            f16x4 hv = { (half_t)pa[i].x, (half_t)pa[i].y, (half_t)pa[i].z, (half_t)pa[i].w };
            *(f16x4*)(&As[r][c * 4]) = hv;
        }
        #pragma unroll
        for (int i = 0; i < 4; i++) {
            int idx = tid + i * 256;
            int nr = idx >> 3, kc = idx & 7;
            *(f16x8*)(&Bs[nr][kc * 8]) = pb[i];
        }
        __syncthreads();

        if (k0 < 192) {
            #pragma unroll
            for (int i = 0; i < 4; i++) {
                int idx = tid + i * 256;
                int r = idx >> 4, c = idx & 15;
                int row = block_row + r; row = row < M ? row : M - 1;
                pa[i] = ((const float4*)(A + (size_t)row * 256 + k0 + 64))[c];
            }
            #pragma unroll
            for (int i = 0; i < 4; i++) {
                int idx = tid + i * 256;
                int nr = idx >> 3, kc = idx & 7;
                pb[i] = *(const f16x8*)(BT + (size_t)nr * 256 + k0 + 64 + kc * 8);
            }
        }

        #pragma unroll
        for (int ks = 0; ks < 2; ks++) {
            f16x8 af[2], bf[4];
            #pragma unroll
            for (int mt = 0; mt < 2; mt++)
                af[mt] = *(const f16x8*)(&As[wm + mt * 16 + l16][ks * 32 + quad * 8]);
            #pragma unroll
            for (int nt = 0; nt < 4; nt++)
                bf[nt] = *(const f16x8*)(&Bs[wn + nt * 16 + l16][ks * 32 + quad * 8]);
            #pragma unroll
            for (int mt = 0; mt < 2; mt++)
                #pragma unroll
                for (int nt = 0; nt < 4; nt++)
                    acc[mt][nt] = __builtin_amdgcn_mfma_f32_16x16x32_f16(af[mt], bf[nt], acc[mt][nt], 0, 0, 0);
        }
        __syncthreads();
    }

    #pragma unroll
    for (int mt = 0; mt < 2; mt++) {
        #pragma unroll
        for (int r = 0; r < 4; r++) {
            int row = block_row + wm + mt * 16 + quad * 4 + r;
            if (row < M) {
                float d = dis[row];
                #pragma unroll
                for (int nt = 0; nt < 4; nt++) {
                    int col = wn + nt * 16 + l16;
                    C[(size_t)row * 128 + col] = (half_t)(acc[mt][nt][r] * d);
                }
            }
        }
    }
}

// ==================== MFMA GEMM2 (pipelined) ====================
__global__ __launch_bounds__(256) void gemm2_mfma(const half_t* __restrict__ A,
                                                  const half_t* __restrict__ BT,
                                                  const float* __restrict__ bmu,
                                                  const float* __restrict__ bvar,
                                                  float* __restrict__ out_mu,
                                                  float* __restrict__ out_sig, int M) {
    __shared__ half_t As[64][72];
    __shared__ half_t Bs[128][72];
    const int tid = threadIdx.x;
    const int block_row = blockIdx.x * 64;
    const int wave = tid >> 6, lane = tid & 63;
    const int wm = (wave & 1) * 32, wn = (wave >> 1) * 64;
    const int l16 = lane & 15, quad = lane >> 4;

    f32x4 acc[2][4] = {};
    f16x8 pa[2], pb[4];

    #pragma unroll
    for (int i = 0; i < 2; i++) {
        int idx = tid + i * 256;
        int r = idx >> 3, kc = idx & 7;
        int row = block_row + r; row = row < M ? row : M - 1;
        pa[i] = *(const f16x8*)(A + (size_t)row * 128 + kc * 8);
    }
    #pragma unroll
    for (int i = 0; i < 4; i++) {
        int idx = tid + i * 256;
        int nr = idx >> 3, kc = idx & 7;
        pb[i] = *(const f16x8*)(BT + (size_t)nr * 128 + kc * 8);
    }

    for (int k0 = 0; k0 < 128; k0 += 64) {
        #pragma unroll
        for (int i = 0; i < 2; i++) {
            int idx = tid + i * 256;
            int r = idx >> 3, kc = idx & 7;
            *(f16x8*)(&As[r][kc * 8]) = pa[i];
        }
        #pragma unroll
        for (int i = 0; i < 4; i++) {
            int idx = tid + i * 256;
            int nr = idx >> 3, kc = idx & 7;
            *(f16x8*)(&Bs[nr][kc * 8]) = pb[i];
        }
        __syncthreads();

        if (k0 < 64) {
            #pragma unroll
            for (int i = 0; i < 2; i++) {
                int idx = tid + i * 256;
                int r = idx >> 3, kc = idx & 7;
                int row = block_row + r; row = row < M ? row : M - 1;
                pa[i] = *(const f16x8*)(A + (size_t)row * 128 + 64 + kc * 8);
            }
            #pragma unroll
            for (int i = 0; i < 4; i++) {
                int idx = tid + i * 256;
                int nr = idx >> 3, kc = idx & 7;
                pb[i] = *(const f16x8*)(BT + (size_t)nr * 128 + 64 + kc * 8);
            }
        }

        #pragma unroll
        for (int ks = 0; ks < 2; ks++) {
            f16x8 af[2], bf[4];
            #pragma unroll
            for (int mt = 0; mt < 2; mt++)
                af[mt] = *(const f16x8*)(&As[wm + mt * 16 + l16][ks * 32 + quad * 8]);
            #pragma unroll
            for (int nt = 0; nt < 4; nt++)
                bf[nt] = *(const f16x8*)(&Bs[wn + nt * 16 + l16][ks * 32 + quad * 8]);
            #pragma unroll
            for (int mt = 0; mt < 2; mt++)
                #pragma unroll
                for (int nt = 0; nt < 4; nt++)
                    acc[mt][nt] = __builtin_amdgcn_mfma_f32_16x16x32_f16(af[mt], bf[nt], acc[mt][nt], 0, 0, 0);
        }
        __syncthreads();
    }

    float bias[4];
    int cols[4];
    #pragma unroll
    for (int nt = 0; nt < 4; nt++) {
        int col = wn + nt * 16 + l16;
        cols[nt] = col;
        bias[nt] = (col < DOUT) ? bmu[col] : bvar[col - DOUT];
    }

    #pragma unroll
    for (int mt = 0; mt < 2; mt++) {
        #pragma unroll
        for (int r = 0; r < 4; r++) {
            int row = block_row + wm + mt * 16 + quad * 4 + r;
            if (row < M) {
                #pragma unroll
                for (int nt = 0; nt < 4; nt++) {
                    int col = cols[nt];
                    float v = acc[mt][nt][r] + bias[nt];
                    if (col < DOUT) out_mu[(size_t)row * DOUT + col] = v;
                    else            out_sig[(size_t)row * DOUT + (col - DOUT)] = v;
                }
            }
        }
    }
}

// ==================== aggregation on pre-scaled features ====================
// acc_i = hin[i] + sum_{s in N(i)} hin[s]          (one gather per edge)
// LAYER1: hout = relu(di*acc + b1)*di   LAYER2: hout = di*acc
template <bool LAYER1>
__global__ __launch_bounds__(256) void agg_kernel(const int* __restrict__ rowptr_end,
                                                  const int* __restrict__ col,
                                                  const float* __restrict__ dis,
                                                  const half_t* __restrict__ hin,
                                                  half_t* __restrict__ hout,
                                                  const float* __restrict__ bias, int n) {
    int node = blockIdx.x * 8 + (threadIdx.x >> 5);
    if (node >= n) return;
    int lane = threadIdx.x & 31;
    int beg = (node == 0) ? 0 : rowptr_end[node - 1];
    int end = rowptr_end[node];
    const f16x4* hv = (const f16x4*)hin;

    f16x4 sv = hv[(size_t)node * 32 + lane];
    float ax = (float)sv[0], ay = (float)sv[1], az = (float)sv[2], aw = (float)sv[3];

    int e = beg;
    for (; e + 3 < end; e += 4) {
        int s0 = col[e], s1 = col[e + 1], s2 = col[e + 2], s3 = col[e + 3];
        f16x4 v0 = hv[(size_t)s0 * 32 + lane];
        f16x4 v1 = hv[(size_t)s1 * 32 + lane];
        f16x4 v2 = hv[(size_t)s2 * 32 + lane];
        f16x4 v3 = hv[(size_t)s3 * 32 + lane];
        ax += (float)v0[0] + (float)v1[0] + (float)v2[0] + (float)v3[0];
        ay += (float)v0[1] + (float)v1[1] + (float)v2[1] + (float)v3[1];
        az += (float)v0[2] + (float)v1[2] + (float)v2[2] + (float)v3[2];
        aw += (float)v0[3] + (float)v1[3] + (float)v2[3] + (float)v3[3];
    }
    for (; e < end; e++) {
        int s0 = col[e];
        f16x4 v0 = hv[(size_t)s0 * 32 + lane];
        ax += (float)v0[0]; ay += (float)v0[1]; az += (float)v0[2]; aw += (float)v0[3];
    }

    float di = dis[node];
    if (LAYER1) {
        const float4 b = ((const float4*)bias)[lane];
        ax = ax * di + b.x; ay = ay * di + b.y; az = az * di + b.z; aw = aw * di + b.w;
        ax = (ax > 0.f ? ax : 0.f) * di;
        ay = (ay > 0.f ? ay : 0.f) * di;
        az = (az > 0.f ? az : 0.f) * di;
        aw = (aw > 0.f ? aw : 0.f) * di;
    } else {
        ax *= di; ay *= di; az *= di; aw *= di;
    }
    f16x4 o = { (half_t)ax, (half_t)ay, (half_t)az, (half_t)aw };
    ((f16x4*)hout)[(size_t)node * 32 + lane] = o;
}

extern "C" void kernel_launch(void* const* d_in, const int* in_sizes, int n_in,
                              void* d_out, int out_size, void* d_ws, size_t ws_size,
                              hipStream_t stream) {
    const float* x    = (const float*)d_in[0];
    const int*   ei   = (const int*)d_in[1];
    const float* W1   = (const float*)d_in[2];
    const float* b1   = (const float*)d_in[3];
    const float* Wmu  = (const float*)d_in[4];
    const float* bmu  = (const float*)d_in[5];
    const float* Wvar = (const float*)d_in[6];
    const float* bvar = (const float*)d_in[7];

    const int n = in_sizes[0] / 256;     // 100000
    const int E = in_sizes[1] / 2;       // 1600000
    const int* src = ei;
    const int* dst = ei + E;

    const int NB      = (n + 255) >> NB_SHIFT;       // 391
    const int nblocks = (E + CHUNK - 1) / CHUNK;     // 196
    const int flat    = NB * nblocks;
    const int nb_scan = (flat + 1023) / 1024;        // 75 (<= 1024)

    char* ws = (char*)d_ws;
    size_t off = 0;
    auto alloc = [&](size_t bytes) { void* p = ws + off; off = (off + bytes + 255) & ~(size_t)255; return p; };
    float*  dis     = (float*) alloc((size_t)n * 4);
    int*    rowptr  = (int*)   alloc((size_t)n * 4);
    int*    counts  = (int*)   alloc((size_t)flat * 4);
    int*    offsets = (int*)   alloc((size_t)flat * 4);
    int*    bsum    = (int*)   alloc((size_t)nb_scan * 4 + 256);
    int2*   binned  = (int2*)  alloc((size_t)E * 8);
    int*    col     = (int*)   alloc((size_t)E * 4);
    half_t* W1T     = (half_t*)alloc((size_t)256 * HID * 2);
    half_t* WcatT   = (half_t*)alloc((size_t)HID * HID * 2);
    half_t* hs      = (half_t*)alloc((size_t)n * HID * 2);  // gemm1 out (pre-scaled); reused as agg2
    half_t* h1s     = (half_t*)alloc((size_t)n * HID * 2);  // relu out (pre-scaled)
    half_t* agg2    = hs;                                   // alias: hs dead after agg1

    float* out_mu  = (float*)d_out;
    float* out_sig = (float*)d_out + (size_t)n * DOUT;

    // CSR build
    bincount_kernel<<<nblocks, 256, 0, stream>>>(dst, counts, E, nblocks, NB);
    scan1_kernel<<<nb_scan, 256, 0, stream>>>(counts, offsets, bsum, flat);
    scan2_kernel<<<1, 1024, 0, stream>>>(bsum, nb_scan);
    scan3_kernel<<<(flat + 255) / 256, 256, 0, stream>>>(offsets, bsum, flat);
    binscatter_kernel<<<nblocks, 1024, 0, stream>>>(src, dst, offsets, binned, E, nblocks, NB);
    csrbuild_kernel<<<NB, 256, 0, stream>>>(binned, offsets, rowptr, col, dis, E, nblocks, NB, n);

    // weights
    w1t_kernel<<<(256 * HID) / 256, 256, 0, stream>>>(W1, W1T);
    wcatt_kernel<<<(HID * HID) / 256, 256, 0, stream>>>(Wmu, Wvar, WcatT);

    // dense + sparse pipeline
    gemm1_mfma<<<(n + 63) / 64, 256, 0, stream>>>(x, W1T, dis, hs, n);
    agg_kernel<true><<<(n + 7) / 8, 256, 0, stream>>>(rowptr, col, dis, hs, h1s, b1, n);
    agg_kernel<false><<<(n + 7) / 8, 256, 0, stream>>>(rowptr, col, dis, h1s, agg2, nullptr, n);
    gemm2_mfma<<<(n + 63) / 64, 256, 0, stream>>>(agg2, WcatT, bmu, bvar, out_mu, out_sig, n);
}